// Round 7
// baseline (283.803 us; speedup 1.0000x reference)
//
#include <hip/hip_runtime.h>
#include <hip/hip_bf16.h>
#include <stdint.h>

// ---------------------------------------------------------------------------
// wannModel: x0 = x@Ws^T + bs;  h_{l+1} = relu(h_l@W_l^T + b_l) + x0 (32x);
//            out = softmax(h@Wo^T + bo)  over 64 classes.
//
// Transposed-orientation MFMA chain (out^T = W * h^T). k-index mismatch
// absorbed by pre-permuting weights' k axis (pi) in a prep kernel.
//
// R12 post-mortem: x0-in-LDS works (no spill, VGPR 104) but (a) x0 layout
// lane*2 u32 = even-banks-only -> 8.78M bank conflicts, (b) mt=4 gives only
// 2 waves/SIMD -> L2 latency exposed (MfmaUtil 28%).
// R13: mt=2 + x0-in-LDS => joint reg demand ~112 FITS launch_bounds(256,4)
// (128 budget) for the first time:
//   - 1024 blocks = exactly 4 blocks/CU: ZERO dispatch tail (the R7/R10 goal)
//   - 16 waves/CU = 4 waves/SIMD: L2 latency hidden 4-deep
//   - weights L2-direct, no barriers, free-running waves (L1-amplified:
//     12 wave-streams/CU share the same 32KB/layer sequence)
//   - x0 LDS layout [pair][plane][lane]: 4B lane stride, reads +0/+64
//     (ds_read2_b32), 2-way bank aliasing = free (fixes R12's 4-way)
//   - LDS 32KB/block (4 waves x 8KB x0, reused as softmax scratch)
// Floors: MFMA 62us, L2 125us (less w/ L1), VALU ~50us -> target 150-175us.
// ---------------------------------------------------------------------------

typedef short bs8 __attribute__((ext_vector_type(8)));   // 8 x bf16 bits
typedef float f32x4 __attribute__((ext_vector_type(4)));

union Frag { bs8 v; uint32_t u[4]; };
union F4   { float4 f; f32x4 v; };

__device__ __forceinline__ uint32_t cvtpk(float lo, float hi) {
#if __has_builtin(__builtin_amdgcn_cvt_pk_bf16_f32)
  auto r = __builtin_amdgcn_cvt_pk_bf16_f32(lo, hi);   // dst.lo=cvt(lo)
  uint32_t u; __builtin_memcpy(&u, &r, 4);
  return u;
#else
  union { float f; uint32_t u; } a, b; a.f = lo; b.f = hi;
  uint32_t ra = a.u + 0x7fffu + ((a.u >> 16) & 1u);    // RNE, no NaN check
  uint32_t rb = b.u + 0x7fffu + ((b.u >> 16) & 1u);
  return (ra >> 16) | (rb & 0xffff0000u);
#endif
}

// ---------------------------------------------------------------------------
// Preprocess. Chunk layout in d_ws (uint16 units, 8320 elems = 16640 B each):
//   chunk c base = c*8320.  [0,8192) = weight frags (4 ntloc x 4 kt),
//   [8192,8320) = 256 B bias (64 floats for this half-layer).
// Chunks: 0,1 = W_start halves (NATURAL k) + b_start halves;
//         2+2l+h = layer l half h (PI-permuted k) + layer_b[l] half h;
//         66 = W_out (4 nt, PI-permuted) + b_out (64 floats).
// Weight element in chunk: ((ntloc*4+kt)*64 + lane)*8 + j.
// ---------------------------------------------------------------------------
__global__ void prep_frags(const float* __restrict__ w_start,
                           const float* __restrict__ b_start,
                           const float* __restrict__ masked_w,
                           const float* __restrict__ layer_b,
                           const float* __restrict__ w_out,
                           const float* __restrict__ b_out,
                           uint16_t* __restrict__ dst) {
  int t = blockIdx.x * 256 + threadIdx.x;
  if (t >= 69680) return;
  if (t >= 68608) {                            // bias floats, 4 per thread
    int f = (t - 68608) * 4;
    int c, off; const float* src;
    if (f < 128)       { c = f >> 6;               off = f & 63; src = b_start + f; }
    else if (f < 4224) { int g = f - 128;  c = 2 + (g >> 6); off = g & 63; src = layer_b + g; }
    else               { int g = f - 4224; c = 66;           off = g;      src = b_out + g; }
    float4 v = *reinterpret_cast<const float4*>(src);
    *reinterpret_cast<float4*>(
        reinterpret_cast<float*>(dst + (size_t)c * 8320 + 8192) + off) = v;
    return;
  }
  int lane = t & 63, kt = (t >> 6) & 3, q = lane >> 4, m15 = lane & 15;
  float f[8];
  int c, ntloc;
  if (t < 2048) {                              // W_start (natural k)
    int nt = (t >> 8) & 7;
    c = nt >> 2; ntloc = nt & 3;
    const float* s = w_start + (nt * 16 + m15) * 128 + q * 8 + kt * 32;
    #pragma unroll
    for (int j = 0; j < 8; ++j) f[j] = s[j];
  } else if (t < 67584) {                      // chain (pi-permuted k)
    int t2 = t - 2048, l = t2 >> 11, nt = (t2 >> 8) & 7;
    c = 2 + 2 * l + (nt >> 2); ntloc = nt & 3;
    const float* s = masked_w + ((l * 128) + nt * 16 + m15) * 128 + q * 4 + kt * 32;
    #pragma unroll
    for (int j = 0; j < 8; ++j) f[j] = s[(j & 3) + 16 * (j >> 2)];
  } else {                                     // W_out (pi-permuted k)
    int t3 = t - 67584, nt = (t3 >> 8) & 3;
    c = 66; ntloc = nt;
    const float* s = w_out + (nt * 16 + m15) * 128 + q * 4 + kt * 32;
    #pragma unroll
    for (int j = 0; j < 8; ++j) f[j] = s[(j & 3) + 16 * (j >> 2)];
  }
  uint4 o;
  o.x = cvtpk(f[0], f[1]); o.y = cvtpk(f[2], f[3]);
  o.z = cvtpk(f[4], f[5]); o.w = cvtpk(f[6], f[7]);
  *reinterpret_cast<uint4*>(dst + (size_t)c * 8320 +
                            ((ntloc * 4 + kt) * 64 + lane) * 8) = o;
}

// ---------------------------------------------------------------------------
// Main kernel: 1024 blocks x 256 threads (4 waves; wave owns 32 batch cols
// = 2 m-tiles of 16). NO barriers, NO weight staging: weights straight from
// L2/L1. LDS 32KB = 4 waves x 8KB private x0 (bf16 words, layout
// [pair=mt*8+nt][plane 0/1][lane], 4B lane stride -> conflict-free),
// reused as softmax scratch. Exactly 4 blocks/CU (16 waves/CU), one
// dispatch round, zero tail; all waves free-run.
// ---------------------------------------------------------------------------
extern __shared__ uint16_t lds[];

__global__ void __launch_bounds__(256, 4)
wann_main(const float* __restrict__ x,
          const uint16_t* __restrict__ wfrag,
          float* __restrict__ out) {
  const int tid  = threadIdx.x;
  const int lane = tid & 63;
  const int wave = tid >> 6;
  const int q    = lane >> 4;
  const int mc   = lane & 15;
  const long batch0 = (long)blockIdx.x * 128 + wave * 32;
  const f32x4 zero4 = {0.f, 0.f, 0.f, 0.f};

  const int lane8 = lane * 8;

  // per-wave private x0 store: 2048 u32 (8KB).
  // pair pr=mt*8+nt at u32 offset pr*128 + lane (plane 0) / +64 (plane 1).
  uint32_t* x0l = reinterpret_cast<uint32_t*>(lds) + wave * 2048;

  // ---- load x fragments (natural k: B[k=8q+j+32kt][batch=mc]) ----
  Frag xf[2][4];
  #pragma unroll
  for (int mt = 0; mt < 2; ++mt) {
    const float* xrow = x + (batch0 + mt * 16 + mc) * 128 + q * 8;
    #pragma unroll
    for (int kt = 0; kt < 4; ++kt) {
      float4 a = *reinterpret_cast<const float4*>(xrow + kt * 32);
      float4 b = *reinterpret_cast<const float4*>(xrow + kt * 32 + 4);
      xf[mt][kt].u[0] = cvtpk(a.x, a.y);
      xf[mt][kt].u[1] = cvtpk(a.z, a.w);
      xf[mt][kt].u[2] = cvtpk(b.x, b.y);
      xf[mt][kt].u[3] = cvtpk(b.z, b.w);
    }
  }

  Frag hA[2][4], hB[2][4];

  // ---- start layer: chunks 0,1 (natural k); x0 -> LDS and hA ----
  #pragma unroll
  for (int nt = 0; nt < 8; ++nt) {
    const uint16_t* cb = wfrag + (size_t)(nt >> 2) * 8320;   // chunk base
    const int ntloc = nt & 3;
    const uint16_t* wb = cb + ntloc * 2048 + lane8;
    F4 bb;
    bb.f = *reinterpret_cast<const float4*>(
        reinterpret_cast<const float*>(cb + 8192) + ntloc * 16 + q * 4);
    Frag wf0, wf1, wf2, wf3;
    wf0.v = *reinterpret_cast<const bs8*>(wb);
    wf1.v = *reinterpret_cast<const bs8*>(wb + 512);
    wf2.v = *reinterpret_cast<const bs8*>(wb + 1024);
    wf3.v = *reinterpret_cast<const bs8*>(wb + 1536);
    f32x4 acc[2];
    __builtin_amdgcn_s_setprio(1);
    #pragma unroll
    for (int mt = 0; mt < 2; ++mt)
      acc[mt] = __builtin_amdgcn_mfma_f32_16x16x32_bf16(wf0.v, xf[mt][0].v, bb.v, 0, 0, 0);
    #pragma unroll
    for (int mt = 0; mt < 2; ++mt)
      acc[mt] = __builtin_amdgcn_mfma_f32_16x16x32_bf16(wf1.v, xf[mt][1].v, acc[mt], 0, 0, 0);
    #pragma unroll
    for (int mt = 0; mt < 2; ++mt)
      acc[mt] = __builtin_amdgcn_mfma_f32_16x16x32_bf16(wf2.v, xf[mt][2].v, acc[mt], 0, 0, 0);
    #pragma unroll
    for (int mt = 0; mt < 2; ++mt)
      acc[mt] = __builtin_amdgcn_mfma_f32_16x16x32_bf16(wf3.v, xf[mt][3].v, acc[mt], 0, 0, 0);
    __builtin_amdgcn_s_setprio(0);
    const int p = nt >> 1, h = nt & 1;
    #pragma unroll
    for (int mt = 0; mt < 2; ++mt) {
      uint32_t w0 = cvtpk(acc[mt][0], acc[mt][1]);
      uint32_t w1 = cvtpk(acc[mt][2], acc[mt][3]);
      hA[mt][p].u[2 * h + 0] = w0;
      hA[mt][p].u[2 * h + 1] = w1;
      uint32_t* xp = x0l + (mt * 8 + nt) * 128 + lane;
      xp[0]  = w0;
      xp[64] = w1;
    }
  }

  // ---- chain layer body (weights from L2/L1, x0 from private LDS) ----
  auto chain_layer = [&](uint32_t l, Frag (&hin)[2][4], Frag (&hout)[2][4]) {
    const uint16_t* lb = wfrag + (size_t)(2 + 2 * l) * 8320;
    #pragma unroll
    for (int nt = 0; nt < 8; ++nt) {
      const uint16_t* cb = lb + (size_t)(nt >> 2) * 8320;
      const int ntloc = nt & 3;
      const uint16_t* wb = cb + ntloc * 2048 + lane8;
      F4 bb;
      bb.f = *reinterpret_cast<const float4*>(
          reinterpret_cast<const float*>(cb + 8192) + ntloc * 16 + q * 4);
      Frag wf0, wf1, wf2, wf3;
      wf0.v = *reinterpret_cast<const bs8*>(wb);
      wf1.v = *reinterpret_cast<const bs8*>(wb + 512);
      wf2.v = *reinterpret_cast<const bs8*>(wb + 1024);
      wf3.v = *reinterpret_cast<const bs8*>(wb + 1536);
      f32x4 acc[2];
      __builtin_amdgcn_s_setprio(1);
      #pragma unroll
      for (int mt = 0; mt < 2; ++mt)
        acc[mt] = __builtin_amdgcn_mfma_f32_16x16x32_bf16(wf0.v, hin[mt][0].v, bb.v, 0, 0, 0);
      #pragma unroll
      for (int mt = 0; mt < 2; ++mt)
        acc[mt] = __builtin_amdgcn_mfma_f32_16x16x32_bf16(wf1.v, hin[mt][1].v, acc[mt], 0, 0, 0);
      #pragma unroll
      for (int mt = 0; mt < 2; ++mt)
        acc[mt] = __builtin_amdgcn_mfma_f32_16x16x32_bf16(wf2.v, hin[mt][2].v, acc[mt], 0, 0, 0);
      #pragma unroll
      for (int mt = 0; mt < 2; ++mt)
        acc[mt] = __builtin_amdgcn_mfma_f32_16x16x32_bf16(wf3.v, hin[mt][3].v, acc[mt], 0, 0, 0);
      __builtin_amdgcn_s_setprio(0);
      const int p = nt >> 1, h = nt & 1;
      #pragma unroll
      for (int mt = 0; mt < 2; ++mt) {
        const uint32_t* xp = x0l + (mt * 8 + nt) * 128 + lane;
        uint32_t xw0 = xp[0];
        uint32_t xw1 = xp[64];
        f32x4 r = __builtin_elementwise_max(acc[mt], zero4);
        f32x4 xv;
        xv[0] = __uint_as_float(xw0 << 16);
        xv[1] = __uint_as_float(xw0 & 0xffff0000u);
        xv[2] = __uint_as_float(xw1 << 16);
        xv[3] = __uint_as_float(xw1 & 0xffff0000u);
        r = r + xv;
        hout[mt][p].u[2 * h + 0] = cvtpk(r[0], r[1]);
        hout[mt][p].u[2 * h + 1] = cvtpk(r[2], r[3]);
      }
    }
  };

  // ---- 32 layers; h ping-pong via 2x unroll ----
  #pragma unroll 1
  for (uint32_t l = 0; l < 32; l += 2) {
    chain_layer(l, hA, hB);
    chain_layer(l + 1, hB, hA);
  }

  // ---- output layer: chunk 66 (W_out + b_out) from L2 ----
  const uint16_t* wo = wfrag + (size_t)66 * 8320;
  const float* bob = reinterpret_cast<const float*>(wo + 8192);
  f32x4 ao[4][2];  // [nt][mt]
  #pragma unroll
  for (int nt = 0; nt < 4; ++nt) {
    const uint16_t* wb = wo + nt * 2048 + lane8;
    F4 bo;
    bo.f = *reinterpret_cast<const float4*>(bob + nt * 16 + q * 4);
    Frag wf0, wf1, wf2, wf3;
    wf0.v = *reinterpret_cast<const bs8*>(wb);
    wf1.v = *reinterpret_cast<const bs8*>(wb + 512);
    wf2.v = *reinterpret_cast<const bs8*>(wb + 1024);
    wf3.v = *reinterpret_cast<const bs8*>(wb + 1536);
    __builtin_amdgcn_s_setprio(1);
    #pragma unroll
    for (int mt = 0; mt < 2; ++mt)
      ao[nt][mt] = __builtin_amdgcn_mfma_f32_16x16x32_bf16(wf0.v, hA[mt][0].v, bo.v, 0, 0, 0);
    #pragma unroll
    for (int mt = 0; mt < 2; ++mt)
      ao[nt][mt] = __builtin_amdgcn_mfma_f32_16x16x32_bf16(wf1.v, hA[mt][1].v, ao[nt][mt], 0, 0, 0);
    #pragma unroll
    for (int mt = 0; mt < 2; ++mt)
      ao[nt][mt] = __builtin_amdgcn_mfma_f32_16x16x32_bf16(wf2.v, hA[mt][2].v, ao[nt][mt], 0, 0, 0);
    #pragma unroll
    for (int mt = 0; mt < 2; ++mt)
      ao[nt][mt] = __builtin_amdgcn_mfma_f32_16x16x32_bf16(wf3.v, hA[mt][3].v, ao[nt][mt], 0, 0, 0);
    __builtin_amdgcn_s_setprio(0);
  }

  // ---- softmax over 64 classes + transposed store via LDS scratch ----
  // x0 region is dead now; reuse the wave's private 8KB as scratch
  // (16x68 floats = 4352 B <= 8192 B).
  float* tr = reinterpret_cast<float*>(x0l);
  #pragma unroll
  for (int mt = 0; mt < 2; ++mt) {
    float e[16];
    float M = -3.0e38f;
    #pragma unroll
    for (int nt = 0; nt < 4; ++nt)
      #pragma unroll
      for (int r = 0; r < 4; ++r)
        M = fmaxf(M, ao[nt][mt][r]);
    M = fmaxf(M, __shfl_xor(M, 16, 64));
    M = fmaxf(M, __shfl_xor(M, 32, 64));
    float S = 0.0f;
    #pragma unroll
    for (int nt = 0; nt < 4; ++nt)
      #pragma unroll
      for (int r = 0; r < 4; ++r) {
        float t = exp2f((ao[nt][mt][r] - M) * 1.4426950408889634f);
        e[nt * 4 + r] = t;
        S += t;
      }
    S += __shfl_xor(S, 16, 64);
    S += __shfl_xor(S, 32, 64);
    const float inv = 1.0f / S;
    #pragma unroll
    for (int nt = 0; nt < 4; ++nt) {
      float4 pv;
      pv.x = e[nt * 4 + 0] * inv;
      pv.y = e[nt * 4 + 1] * inv;
      pv.z = e[nt * 4 + 2] * inv;
      pv.w = e[nt * 4 + 3] * inv;
      *reinterpret_cast<float4*>(tr + mc * 68 + nt * 16 + q * 4) = pv;
    }
    __asm__ volatile("s_waitcnt lgkmcnt(0)" ::: "memory");
    #pragma unroll
    for (int it = 0; it < 4; ++it) {
      int row = it * 4 + (lane >> 4);
      float4 v = *reinterpret_cast<const float4*>(tr + row * 68 + (lane & 15) * 4);
      long gr = batch0 + mt * 16 + row;
      *reinterpret_cast<float4*>(out + gr * 64 + (lane & 15) * 4) = v;
    }
    __asm__ volatile("s_waitcnt lgkmcnt(0)" ::: "memory");
  }
}

// ---------------------------------------------------------------------------
extern "C" void kernel_launch(void* const* d_in, const int* in_sizes, int n_in,
                              void* d_out, int out_size, void* d_ws, size_t ws_size,
                              hipStream_t stream) {
  const float* x        = (const float*)d_in[0];
  const float* w_start  = (const float*)d_in[1];
  const float* b_start  = (const float*)d_in[2];
  const float* masked_w = (const float*)d_in[3];
  const float* layer_b  = (const float*)d_in[4];
  const float* w_out    = (const float*)d_in[5];
  const float* b_out    = (const float*)d_in[6];
  uint16_t* wfrag = (uint16_t*)d_ws;   // 67 chunks x 16640 B = 1,114,880 B

  prep_frags<<<273, 256, 0, stream>>>(w_start, b_start, masked_w, layer_b,
                                      w_out, b_out, wfrag);
  wann_main<<<1024, 256, 32768, stream>>>(x, wfrag, (float*)d_out);
}

// Round 8
// 283.045 us; speedup vs baseline: 1.0027x; 1.0027x over previous
//
#include <hip/hip_runtime.h>
#include <hip/hip_bf16.h>
#include <stdint.h>

// ---------------------------------------------------------------------------
// wannModel: x0 = x@Ws^T + bs;  h_{l+1} = relu(h_l@W_l^T + b_l) + x0 (32x);
//            out = softmax(h@Wo^T + bo)  over 64 classes.
//
// Transposed-orientation MFMA chain (out^T = W * h^T). k-index mismatch
// absorbed by pre-permuting weights' k axis (pi) in a prep kernel.
//
// R13 post-mortem: geometry landed (zero tail, no spill, conflicts fixed)
// but dur flat at 216us. VGPR_Count=56 with a 128 budget => compiler issued
// weight loads just-in-time; ~86us of wall is exposed L2 latency (VALUBusy
// 60% includes MFMA 30%; each pipe only ~30% busy).
// R14: explicit 1-deep register prefetch. Two rolling groups rg[2] (4xbs8
// weights + f32x4 bias, ~20 regs/set); iteration nt ISSUES loads for nt+1
// before consuming nt (textually interleaved); nt=7 prefetches the NEXT
// layer's group 0 (layer 31 prefetches W_out; output layer consumes it).
// x0 ds_reads hoisted above the MFMA cluster. Consume waits on loads issued
// one full iteration earlier: 4 waves/SIMD x ~76cy = ~300cy cover >= L2
// latency. Reg inventory ~126 <= 128 budget.
// ---------------------------------------------------------------------------

typedef short bs8 __attribute__((ext_vector_type(8)));   // 8 x bf16 bits
typedef float f32x4 __attribute__((ext_vector_type(4)));

union Frag { bs8 v; uint32_t u[4]; };
union F4   { float4 f; f32x4 v; };

__device__ __forceinline__ uint32_t cvtpk(float lo, float hi) {
#if __has_builtin(__builtin_amdgcn_cvt_pk_bf16_f32)
  auto r = __builtin_amdgcn_cvt_pk_bf16_f32(lo, hi);   // dst.lo=cvt(lo)
  uint32_t u; __builtin_memcpy(&u, &r, 4);
  return u;
#else
  union { float f; uint32_t u; } a, b; a.f = lo; b.f = hi;
  uint32_t ra = a.u + 0x7fffu + ((a.u >> 16) & 1u);    // RNE, no NaN check
  uint32_t rb = b.u + 0x7fffu + ((b.u >> 16) & 1u);
  return (ra >> 16) | (rb & 0xffff0000u);
#endif
}

// ---------------------------------------------------------------------------
// Preprocess. Chunk layout in d_ws (uint16 units, 8320 elems = 16640 B each):
//   chunk c base = c*8320.  [0,8192) = weight frags (4 ntloc x 4 kt),
//   [8192,8320) = 256 B bias (64 floats for this half-layer).
// Chunks: 0,1 = W_start halves (NATURAL k) + b_start halves;
//         2+2l+h = layer l half h (PI-permuted k) + layer_b[l] half h;
//         66 = W_out (4 nt, PI-permuted) + b_out (64 floats).
// Weight element in chunk: ((ntloc*4+kt)*64 + lane)*8 + j.
// ---------------------------------------------------------------------------
__global__ void prep_frags(const float* __restrict__ w_start,
                           const float* __restrict__ b_start,
                           const float* __restrict__ masked_w,
                           const float* __restrict__ layer_b,
                           const float* __restrict__ w_out,
                           const float* __restrict__ b_out,
                           uint16_t* __restrict__ dst) {
  int t = blockIdx.x * 256 + threadIdx.x;
  if (t >= 69680) return;
  if (t >= 68608) {                            // bias floats, 4 per thread
    int f = (t - 68608) * 4;
    int c, off; const float* src;
    if (f < 128)       { c = f >> 6;               off = f & 63; src = b_start + f; }
    else if (f < 4224) { int g = f - 128;  c = 2 + (g >> 6); off = g & 63; src = layer_b + g; }
    else               { int g = f - 4224; c = 66;           off = g;      src = b_out + g; }
    float4 v = *reinterpret_cast<const float4*>(src);
    *reinterpret_cast<float4*>(
        reinterpret_cast<float*>(dst + (size_t)c * 8320 + 8192) + off) = v;
    return;
  }
  int lane = t & 63, kt = (t >> 6) & 3, q = lane >> 4, m15 = lane & 15;
  float f[8];
  int c, ntloc;
  if (t < 2048) {                              // W_start (natural k)
    int nt = (t >> 8) & 7;
    c = nt >> 2; ntloc = nt & 3;
    const float* s = w_start + (nt * 16 + m15) * 128 + q * 8 + kt * 32;
    #pragma unroll
    for (int j = 0; j < 8; ++j) f[j] = s[j];
  } else if (t < 67584) {                      // chain (pi-permuted k)
    int t2 = t - 2048, l = t2 >> 11, nt = (t2 >> 8) & 7;
    c = 2 + 2 * l + (nt >> 2); ntloc = nt & 3;
    const float* s = masked_w + ((l * 128) + nt * 16 + m15) * 128 + q * 4 + kt * 32;
    #pragma unroll
    for (int j = 0; j < 8; ++j) f[j] = s[(j & 3) + 16 * (j >> 2)];
  } else {                                     // W_out (pi-permuted k)
    int t3 = t - 67584, nt = (t3 >> 8) & 3;
    c = 66; ntloc = nt;
    const float* s = w_out + (nt * 16 + m15) * 128 + q * 4 + kt * 32;
    #pragma unroll
    for (int j = 0; j < 8; ++j) f[j] = s[(j & 3) + 16 * (j >> 2)];
  }
  uint4 o;
  o.x = cvtpk(f[0], f[1]); o.y = cvtpk(f[2], f[3]);
  o.z = cvtpk(f[4], f[5]); o.w = cvtpk(f[6], f[7]);
  *reinterpret_cast<uint4*>(dst + (size_t)c * 8320 +
                            ((ntloc * 4 + kt) * 64 + lane) * 8) = o;
}

// ---------------------------------------------------------------------------
// Main kernel: 1024 blocks x 256 threads (4 waves; wave owns 32 batch cols
// = 2 m-tiles of 16). NO barriers, NO LDS weight staging: weights from
// L2/L1 via explicit 1-deep register prefetch. LDS 32KB = 4 waves x 8KB
// private x0 ([pair][plane][lane], 4B lane stride, conflict-free), reused
// as softmax scratch. Exactly 4 blocks/CU (16 waves/CU), zero tail.
// ---------------------------------------------------------------------------
extern __shared__ uint16_t lds[];

__global__ void __launch_bounds__(256, 4)
wann_main(const float* __restrict__ x,
          const uint16_t* __restrict__ wfrag,
          float* __restrict__ out) {
  const int tid  = threadIdx.x;
  const int lane = tid & 63;
  const int wave = tid >> 6;
  const int q    = lane >> 4;
  const int mc   = lane & 15;
  const long batch0 = (long)blockIdx.x * 128 + wave * 32;
  const f32x4 zero4 = {0.f, 0.f, 0.f, 0.f};

  const int lane8 = lane * 8;

  // per-wave private x0 store: 2048 u32 (8KB).
  // pair pr=mt*8+nt at u32 offset pr*128 + lane (plane 0) / +64 (plane 1).
  uint32_t* x0l = reinterpret_cast<uint32_t*>(lds) + wave * 2048;

  // ---- load x fragments (natural k: B[k=8q+j+32kt][batch=mc]) ----
  Frag xf[2][4];
  #pragma unroll
  for (int mt = 0; mt < 2; ++mt) {
    const float* xrow = x + (batch0 + mt * 16 + mc) * 128 + q * 8;
    #pragma unroll
    for (int kt = 0; kt < 4; ++kt) {
      float4 a = *reinterpret_cast<const float4*>(xrow + kt * 32);
      float4 b = *reinterpret_cast<const float4*>(xrow + kt * 32 + 4);
      xf[mt][kt].u[0] = cvtpk(a.x, a.y);
      xf[mt][kt].u[1] = cvtpk(a.z, a.w);
      xf[mt][kt].u[2] = cvtpk(b.x, b.y);
      xf[mt][kt].u[3] = cvtpk(b.z, b.w);
    }
  }

  Frag hA[2][4], hB[2][4];

  // rolling prefetch state: 2 groups of (4 weight frags + bias)
  Frag rg[2][4];
  F4   rbb[2];

  auto ldgrp = [&](const uint16_t* base, int nt, int set) {
    const uint16_t* cb = base + (size_t)(nt >> 2) * 8320;
    const int ntloc = nt & 3;
    const uint16_t* wb = cb + ntloc * 2048 + lane8;
    rg[set][0].v = *reinterpret_cast<const bs8*>(wb);
    rg[set][1].v = *reinterpret_cast<const bs8*>(wb + 512);
    rg[set][2].v = *reinterpret_cast<const bs8*>(wb + 1024);
    rg[set][3].v = *reinterpret_cast<const bs8*>(wb + 1536);
    rbb[set].f = *reinterpret_cast<const float4*>(
        reinterpret_cast<const float*>(cb + 8192) + ntloc * 16 + q * 4);
  };

  // ---- start layer: chunks 0,1 (natural k); x0 -> LDS and hA ----
  #pragma unroll
  for (int nt = 0; nt < 8; ++nt) {
    const uint16_t* cb = wfrag + (size_t)(nt >> 2) * 8320;   // chunk base
    const int ntloc = nt & 3;
    const uint16_t* wb = cb + ntloc * 2048 + lane8;
    F4 bb;
    bb.f = *reinterpret_cast<const float4*>(
        reinterpret_cast<const float*>(cb + 8192) + ntloc * 16 + q * 4);
    Frag wf0, wf1, wf2, wf3;
    wf0.v = *reinterpret_cast<const bs8*>(wb);
    wf1.v = *reinterpret_cast<const bs8*>(wb + 512);
    wf2.v = *reinterpret_cast<const bs8*>(wb + 1024);
    wf3.v = *reinterpret_cast<const bs8*>(wb + 1536);
    f32x4 acc[2];
    __builtin_amdgcn_s_setprio(1);
    #pragma unroll
    for (int mt = 0; mt < 2; ++mt)
      acc[mt] = __builtin_amdgcn_mfma_f32_16x16x32_bf16(wf0.v, xf[mt][0].v, bb.v, 0, 0, 0);
    #pragma unroll
    for (int mt = 0; mt < 2; ++mt)
      acc[mt] = __builtin_amdgcn_mfma_f32_16x16x32_bf16(wf1.v, xf[mt][1].v, acc[mt], 0, 0, 0);
    #pragma unroll
    for (int mt = 0; mt < 2; ++mt)
      acc[mt] = __builtin_amdgcn_mfma_f32_16x16x32_bf16(wf2.v, xf[mt][2].v, acc[mt], 0, 0, 0);
    #pragma unroll
    for (int mt = 0; mt < 2; ++mt)
      acc[mt] = __builtin_amdgcn_mfma_f32_16x16x32_bf16(wf3.v, xf[mt][3].v, acc[mt], 0, 0, 0);
    __builtin_amdgcn_s_setprio(0);
    const int p = nt >> 1, h = nt & 1;
    #pragma unroll
    for (int mt = 0; mt < 2; ++mt) {
      uint32_t w0 = cvtpk(acc[mt][0], acc[mt][1]);
      uint32_t w1 = cvtpk(acc[mt][2], acc[mt][3]);
      hA[mt][p].u[2 * h + 0] = w0;
      hA[mt][p].u[2 * h + 1] = w1;
      uint32_t* xp = x0l + (mt * 8 + nt) * 128 + lane;
      xp[0]  = w0;
      xp[64] = w1;
    }
  }

  // prefetch chain layer 0, group 0 into set 0
  ldgrp(wfrag + (size_t)2 * 8320, 0, 0);

  // ---- chain layer: rolling 1-deep prefetch; entry: rg[0] = (lb, nt0);
  //      exit: rg[0] = (lbn, nt0) ----
  auto chain_layer = [&](const uint16_t* lb, const uint16_t* lbn,
                         Frag (&hin)[2][4], Frag (&hout)[2][4]) {
    #pragma unroll
    for (int nt = 0; nt < 8; ++nt) {
      const int cur = nt & 1, nxt = cur ^ 1;
      if (nt < 7) ldgrp(lb, nt + 1, nxt);      // issue next group's loads
      else        ldgrp(lbn, 0, nxt);          // cross-layer prefetch
      // hoist x0 LDS reads above the MFMA cluster (lgkm covered by MFMAs)
      const uint32_t* xpa = x0l + (0 * 8 + nt) * 128 + lane;
      const uint32_t* xpb = x0l + (1 * 8 + nt) * 128 + lane;
      const uint32_t xa0 = xpa[0], xa1 = xpa[64];
      const uint32_t xb0 = xpb[0], xb1 = xpb[64];
      f32x4 acc[2];
      __builtin_amdgcn_s_setprio(1);
      #pragma unroll
      for (int mt = 0; mt < 2; ++mt)
        acc[mt] = __builtin_amdgcn_mfma_f32_16x16x32_bf16(rg[cur][0].v, hin[mt][0].v, rbb[cur].v, 0, 0, 0);
      #pragma unroll
      for (int mt = 0; mt < 2; ++mt)
        acc[mt] = __builtin_amdgcn_mfma_f32_16x16x32_bf16(rg[cur][1].v, hin[mt][1].v, acc[mt], 0, 0, 0);
      #pragma unroll
      for (int mt = 0; mt < 2; ++mt)
        acc[mt] = __builtin_amdgcn_mfma_f32_16x16x32_bf16(rg[cur][2].v, hin[mt][2].v, acc[mt], 0, 0, 0);
      #pragma unroll
      for (int mt = 0; mt < 2; ++mt)
        acc[mt] = __builtin_amdgcn_mfma_f32_16x16x32_bf16(rg[cur][3].v, hin[mt][3].v, acc[mt], 0, 0, 0);
      __builtin_amdgcn_s_setprio(0);
      const int p = nt >> 1, h = nt & 1;
      {
        f32x4 r = __builtin_elementwise_max(acc[0], zero4);
        f32x4 xv;
        xv[0] = __uint_as_float(xa0 << 16);
        xv[1] = __uint_as_float(xa0 & 0xffff0000u);
        xv[2] = __uint_as_float(xa1 << 16);
        xv[3] = __uint_as_float(xa1 & 0xffff0000u);
        r = r + xv;
        hout[0][p].u[2 * h + 0] = cvtpk(r[0], r[1]);
        hout[0][p].u[2 * h + 1] = cvtpk(r[2], r[3]);
      }
      {
        f32x4 r = __builtin_elementwise_max(acc[1], zero4);
        f32x4 xv;
        xv[0] = __uint_as_float(xb0 << 16);
        xv[1] = __uint_as_float(xb0 & 0xffff0000u);
        xv[2] = __uint_as_float(xb1 << 16);
        xv[3] = __uint_as_float(xb1 & 0xffff0000u);
        r = r + xv;
        hout[1][p].u[2 * h + 0] = cvtpk(r[0], r[1]);
        hout[1][p].u[2 * h + 1] = cvtpk(r[2], r[3]);
      }
    }
  };

  // ---- 32 layers; h ping-pong via 2x unroll; layer 31 prefetches W_out --
  const uint16_t* wo = wfrag + (size_t)66 * 8320;
  #pragma unroll 1
  for (uint32_t l = 0; l < 32; l += 2) {
    const uint16_t* lb0 = wfrag + (size_t)(2 + 2 * l) * 8320;
    const uint16_t* lb1 = lb0 + 2 * 8320;
    const uint16_t* lb2 = (l + 2 < 32) ? (lb1 + 2 * 8320) : wo;
    chain_layer(lb0, lb1, hA, hB);
    chain_layer(lb1, lb2, hB, hA);
  }

  // ---- output layer: chunk 66, rolling prefetch (entry: rg[0]=(wo,0)) ----
  f32x4 ao[4][2];  // [nt][mt]
  #pragma unroll
  for (int nt = 0; nt < 4; ++nt) {
    const int cur = nt & 1, nxt = cur ^ 1;
    if (nt < 3) ldgrp(wo, nt + 1, nxt);
    __builtin_amdgcn_s_setprio(1);
    #pragma unroll
    for (int mt = 0; mt < 2; ++mt)
      ao[nt][mt] = __builtin_amdgcn_mfma_f32_16x16x32_bf16(rg[cur][0].v, hA[mt][0].v, rbb[cur].v, 0, 0, 0);
    #pragma unroll
    for (int mt = 0; mt < 2; ++mt)
      ao[nt][mt] = __builtin_amdgcn_mfma_f32_16x16x32_bf16(rg[cur][1].v, hA[mt][1].v, ao[nt][mt], 0, 0, 0);
    #pragma unroll
    for (int mt = 0; mt < 2; ++mt)
      ao[nt][mt] = __builtin_amdgcn_mfma_f32_16x16x32_bf16(rg[cur][2].v, hA[mt][2].v, ao[nt][mt], 0, 0, 0);
    #pragma unroll
    for (int mt = 0; mt < 2; ++mt)
      ao[nt][mt] = __builtin_amdgcn_mfma_f32_16x16x32_bf16(rg[cur][3].v, hA[mt][3].v, ao[nt][mt], 0, 0, 0);
    __builtin_amdgcn_s_setprio(0);
  }

  // ---- softmax over 64 classes + transposed store via LDS scratch ----
  // x0 region is dead now; reuse the wave's private 8KB as scratch
  // (16x68 floats = 4352 B <= 8192 B).
  float* tr = reinterpret_cast<float*>(x0l);
  #pragma unroll
  for (int mt = 0; mt < 2; ++mt) {
    float e[16];
    float M = -3.0e38f;
    #pragma unroll
    for (int nt = 0; nt < 4; ++nt)
      #pragma unroll
      for (int r = 0; r < 4; ++r)
        M = fmaxf(M, ao[nt][mt][r]);
    M = fmaxf(M, __shfl_xor(M, 16, 64));
    M = fmaxf(M, __shfl_xor(M, 32, 64));
    float S = 0.0f;
    #pragma unroll
    for (int nt = 0; nt < 4; ++nt)
      #pragma unroll
      for (int r = 0; r < 4; ++r) {
        float t = exp2f((ao[nt][mt][r] - M) * 1.4426950408889634f);
        e[nt * 4 + r] = t;
        S += t;
      }
    S += __shfl_xor(S, 16, 64);
    S += __shfl_xor(S, 32, 64);
    const float inv = 1.0f / S;
    #pragma unroll
    for (int nt = 0; nt < 4; ++nt) {
      float4 pv;
      pv.x = e[nt * 4 + 0] * inv;
      pv.y = e[nt * 4 + 1] * inv;
      pv.z = e[nt * 4 + 2] * inv;
      pv.w = e[nt * 4 + 3] * inv;
      *reinterpret_cast<float4*>(tr + mc * 68 + nt * 16 + q * 4) = pv;
    }
    __asm__ volatile("s_waitcnt lgkmcnt(0)" ::: "memory");
    #pragma unroll
    for (int it = 0; it < 4; ++it) {
      int row = it * 4 + (lane >> 4);
      float4 v = *reinterpret_cast<const float4*>(tr + row * 68 + (lane & 15) * 4);
      long gr = batch0 + mt * 16 + row;
      *reinterpret_cast<float4*>(out + gr * 64 + (lane & 15) * 4) = v;
    }
    __asm__ volatile("s_waitcnt lgkmcnt(0)" ::: "memory");
  }
}

// ---------------------------------------------------------------------------
extern "C" void kernel_launch(void* const* d_in, const int* in_sizes, int n_in,
                              void* d_out, int out_size, void* d_ws, size_t ws_size,
                              hipStream_t stream) {
  const float* x        = (const float*)d_in[0];
  const float* w_start  = (const float*)d_in[1];
  const float* b_start  = (const float*)d_in[2];
  const float* masked_w = (const float*)d_in[3];
  const float* layer_b  = (const float*)d_in[4];
  const float* w_out    = (const float*)d_in[5];
  const float* b_out    = (const float*)d_in[6];
  uint16_t* wfrag = (uint16_t*)d_ws;   // 67 chunks x 16640 B = 1,114,880 B

  prep_frags<<<273, 256, 0, stream>>>(w_start, b_start, masked_w, layer_b,
                                      w_out, b_out, wfrag);
  wann_main<<<1024, 256, 32768, stream>>>(x, wfrag, (float*)d_out);
}

// Round 9
// 245.712 us; speedup vs baseline: 1.1550x; 1.1519x over previous
//
#include <hip/hip_runtime.h>
#include <hip/hip_bf16.h>
#include <stdint.h>

// ---------------------------------------------------------------------------
// wannModel: x0 = x@Ws^T + bs;  h_{l+1} = relu(h_l@W_l^T + b_l) + x0 (32x);
//            out = softmax(h@Wo^T + bo)  over 64 classes.
//
// Transposed-orientation MFMA chain (out^T = W * h^T). k-index mismatch
// absorbed by pre-permuting weights' k axis (pi) in a prep kernel. h stays
// in registers across all 32 layers (mt=2: 32 rows/wave, 12 waves/CU).
//
// R14 post-mortem: rolling reg-prefetch spilled (~6MB scratch) and was
// neutral; with MfmaUtil and VALUBusy as SEPARATE pipes, R13 = 90% combined
// busy => the wall is VALU, not latency. R9 (best, 207us) = 83% combined.
// R15: back to R9's structure (LDS-staged weights, counted vmcnt(5),
// triple buffer, 3 blocks/CU) with ONE change: cvtpk via inline-asm
// v_cvt_pk_bf16_f32. gfx950 has the instruction but NO builtin (T12/m240),
// so the #if __has_builtin fallback was emitting ~7 VALU ops per pack;
// 32 packs/layer/wave x 33 layers ~= 25us/SIMD of rounding arithmetic on
// the epilogue critical path. Hardware RNE == fallback RNE (bit-identical).
// ---------------------------------------------------------------------------

typedef short bs8 __attribute__((ext_vector_type(8)));   // 8 x bf16 bits
typedef float f32x4 __attribute__((ext_vector_type(4)));

union Frag { bs8 v; uint32_t u[4]; };
union F4   { float4 f; f32x4 v; };

__device__ __forceinline__ uint32_t cvtpk(float lo, float hi) {
  uint32_t r;
  asm("v_cvt_pk_bf16_f32 %0, %1, %2" : "=v"(r) : "v"(lo), "v"(hi));
  return r;
}

// ---------------------------------------------------------------------------
// Preprocess. Chunk layout in d_ws (uint16 units, 8320 elems = 16640 B each):
//   chunk c base = c*8320.  [0,8192) = weight frags (4 ntloc x 4 kt),
//   [8192,8320) = 256 B bias (64 floats for this half-layer).
// Chunks: 0,1 = W_start halves (NATURAL k) + b_start halves;
//         2+2l+h = layer l half h (PI-permuted k) + layer_b[l] half h;
//         66 = W_out (4 nt, PI-permuted) + b_out (64 floats).
// Weight element in chunk: ((ntloc*4+kt)*64 + lane)*8 + j.
// ---------------------------------------------------------------------------
__global__ void prep_frags(const float* __restrict__ w_start,
                           const float* __restrict__ b_start,
                           const float* __restrict__ masked_w,
                           const float* __restrict__ layer_b,
                           const float* __restrict__ w_out,
                           const float* __restrict__ b_out,
                           uint16_t* __restrict__ dst) {
  int t = blockIdx.x * 256 + threadIdx.x;
  if (t >= 69680) return;
  if (t >= 68608) {                            // bias floats, 4 per thread
    int f = (t - 68608) * 4;
    int c, off; const float* src;
    if (f < 128)       { c = f >> 6;               off = f & 63; src = b_start + f; }
    else if (f < 4224) { int g = f - 128;  c = 2 + (g >> 6); off = g & 63; src = layer_b + g; }
    else               { int g = f - 4224; c = 66;           off = g;      src = b_out + g; }
    float4 v = *reinterpret_cast<const float4*>(src);
    *reinterpret_cast<float4*>(
        reinterpret_cast<float*>(dst + (size_t)c * 8320 + 8192) + off) = v;
    return;
  }
  int lane = t & 63, kt = (t >> 6) & 3, q = lane >> 4, m15 = lane & 15;
  float f[8];
  int c, ntloc;
  if (t < 2048) {                              // W_start (natural k)
    int nt = (t >> 8) & 7;
    c = nt >> 2; ntloc = nt & 3;
    const float* s = w_start + (nt * 16 + m15) * 128 + q * 8 + kt * 32;
    #pragma unroll
    for (int j = 0; j < 8; ++j) f[j] = s[j];
  } else if (t < 67584) {                      // chain (pi-permuted k)
    int t2 = t - 2048, l = t2 >> 11, nt = (t2 >> 8) & 7;
    c = 2 + 2 * l + (nt >> 2); ntloc = nt & 3;
    const float* s = masked_w + ((l * 128) + nt * 16 + m15) * 128 + q * 4 + kt * 32;
    #pragma unroll
    for (int j = 0; j < 8; ++j) f[j] = s[(j & 3) + 16 * (j >> 2)];
  } else {                                     // W_out (pi-permuted k)
    int t3 = t - 67584, nt = (t3 >> 8) & 3;
    c = 66; ntloc = nt;
    const float* s = w_out + (nt * 16 + m15) * 128 + q * 4 + kt * 32;
    #pragma unroll
    for (int j = 0; j < 8; ++j) f[j] = s[(j & 3) + 16 * (j >> 2)];
  }
  uint4 o;
  o.x = cvtpk(f[0], f[1]); o.y = cvtpk(f[2], f[3]);
  o.z = cvtpk(f[4], f[5]); o.w = cvtpk(f[6], f[7]);
  *reinterpret_cast<uint4*>(dst + (size_t)c * 8320 +
                            ((ntloc * 4 + kt) * 64 + lane) * 8) = o;
}

// ---------------------------------------------------------------------------
// Main kernel: 1024 blocks x 256 threads (4 waves; wave owns 32 batch cols
// = 2 m-tiles of 16). LDS 49920B = 3 chunk slots of 8320 uint16.
// Phase(c): s_waitcnt vmcnt(5) -> s_barrier -> stage chunk c+2 -> compute c.
// Loads for c+1 and c+2 stay in flight across the barrier (T3/T4).
// 3 blocks/CU resident; independent blocks cover each other's phases.
// ---------------------------------------------------------------------------
extern __shared__ uint16_t lds[];

#define VMW(N) asm volatile("s_waitcnt vmcnt(" #N ")" ::: "memory")

__global__ void __launch_bounds__(256, 3)
wann_main(const float* __restrict__ x,
          const uint16_t* __restrict__ wfrag,
          float* __restrict__ out) {
  const int tid  = threadIdx.x;
  const int lane = tid & 63;
  const int wave = tid >> 6;
  const int q    = lane >> 4;
  const int mc   = lane & 15;
  const long batch0 = (long)blockIdx.x * 128 + wave * 32;
  const f32x4 zero4 = {0.f, 0.f, 0.f, 0.f};

  auto slotp = [&](uint32_t s) -> uint16_t* { return lds + (size_t)s * 8320; };

  // stage one chunk: 4 x width-16 (weights) + 1 x width-4 (bias) per wave.
  // Exactly 5 vmcnt ops per stage -> counted waits are exact.
  auto stage = [&](uint16_t* dstb, uint32_t c) {
    const uint16_t* srcb = wfrag + (size_t)c * 8320;
    #pragma unroll
    for (int i = 0; i < 4; ++i) {
      __builtin_amdgcn_global_load_lds(
          (const __attribute__((address_space(1))) void*)(srcb + i * 2048 + wave * 512 + lane * 8),
          (__attribute__((address_space(3))) void*)(dstb + i * 2048 + wave * 512),
          16, 0, 0);
    }
    // bias: all 4 waves write the same 256B (same data; benign duplication)
    __builtin_amdgcn_global_load_lds(
        (const __attribute__((address_space(1))) void*)(srcb + 8192 + lane * 2),
        (__attribute__((address_space(3))) void*)(dstb + 8192),
        4, 0, 0);
  };

  auto barx = [&]() {
    asm volatile("" ::: "memory");
    __builtin_amdgcn_s_barrier();
    asm volatile("" ::: "memory");
  };

  // ---- load x fragments (natural k: B[k=8q+j+32kt][batch=mc]) ----
  Frag xf[2][4];
  #pragma unroll
  for (int mt = 0; mt < 2; ++mt) {
    const float* xrow = x + (batch0 + mt * 16 + mc) * 128 + q * 8;
    #pragma unroll
    for (int kt = 0; kt < 4; ++kt) {
      float4 a = *reinterpret_cast<const float4*>(xrow + kt * 32);
      float4 b = *reinterpret_cast<const float4*>(xrow + kt * 32 + 4);
      xf[mt][kt].u[0] = cvtpk(a.x, a.y);
      xf[mt][kt].u[1] = cvtpk(a.z, a.w);
      xf[mt][kt].u[2] = cvtpk(b.x, b.y);
      xf[mt][kt].u[3] = cvtpk(b.z, b.w);
    }
  }

  stage(slotp(0), 0);                        // W_start half 0
  stage(slotp(1), 1);                        // W_start half 1

  Frag x0f[2][4], hA[2][4], hB[2][4];

  // ---- start layer half h: 2 passes; acc init = bias (from chunk LDS) ----
  auto start_half = [&](const uint16_t* buf, int h) {
    const float* bbb = reinterpret_cast<const float*>(buf + 8192);
    #pragma unroll
    for (int pp = 0; pp < 2; ++pp) {
      const int p = 2 * h + pp;
      F4 bb[2];
      #pragma unroll
      for (int ntl = 0; ntl < 2; ++ntl)
        bb[ntl].f = *reinterpret_cast<const float4*>(bbb + (2 * pp + ntl) * 16 + q * 4);
      f32x4 acc[2][2];
      __builtin_amdgcn_s_setprio(1);
      #pragma unroll
      for (int kt = 0; kt < 4; ++kt)
        #pragma unroll
        for (int ntl = 0; ntl < 2; ++ntl) {
          const int ntloc = 2 * pp + ntl;
          Frag wf;
          wf.v = *reinterpret_cast<const bs8*>(buf + ((ntloc * 4 + kt) * 64 + lane) * 8);
          #pragma unroll
          for (int mt = 0; mt < 2; ++mt) {
            f32x4 c = (kt == 0) ? bb[ntl].v : acc[ntl][mt];
            acc[ntl][mt] = __builtin_amdgcn_mfma_f32_16x16x32_bf16(wf.v, xf[mt][kt].v, c, 0, 0, 0);
          }
        }
      __builtin_amdgcn_s_setprio(0);
      #pragma unroll
      for (int mt = 0; mt < 2; ++mt)
        #pragma unroll
        for (int ntl = 0; ntl < 2; ++ntl) {
          x0f[mt][p].u[2 * ntl + 0] = cvtpk(acc[ntl][mt][0], acc[ntl][mt][1]);
          x0f[mt][p].u[2 * ntl + 1] = cvtpk(acc[ntl][mt][2], acc[ntl][mt][3]);
        }
    }
  };

  // ---- chain layer half h: hout = bf16(relu(acc_with_bias) + x0) ----
  auto chain_half = [&](const uint16_t* buf, int h,
                        Frag (&hin)[2][4], Frag (&hout)[2][4]) {
    const float* bbb = reinterpret_cast<const float*>(buf + 8192);
    #pragma unroll
    for (int pp = 0; pp < 2; ++pp) {
      const int p = 2 * h + pp;
      F4 bb[2];
      #pragma unroll
      for (int ntl = 0; ntl < 2; ++ntl)
        bb[ntl].f = *reinterpret_cast<const float4*>(bbb + (2 * pp + ntl) * 16 + q * 4);
      f32x4 acc[2][2];
      __builtin_amdgcn_s_setprio(1);
      #pragma unroll
      for (int kt = 0; kt < 4; ++kt)
        #pragma unroll
        for (int ntl = 0; ntl < 2; ++ntl) {
          const int ntloc = 2 * pp + ntl;
          Frag wf;
          wf.v = *reinterpret_cast<const bs8*>(buf + ((ntloc * 4 + kt) * 64 + lane) * 8);
          #pragma unroll
          for (int mt = 0; mt < 2; ++mt) {
            f32x4 c = (kt == 0) ? bb[ntl].v : acc[ntl][mt];
            acc[ntl][mt] = __builtin_amdgcn_mfma_f32_16x16x32_bf16(wf.v, hin[mt][kt].v, c, 0, 0, 0);
          }
        }
      __builtin_amdgcn_s_setprio(0);
      #pragma unroll
      for (int mt = 0; mt < 2; ++mt)
        #pragma unroll
        for (int ntl = 0; ntl < 2; ++ntl) {
          f32x4 r = __builtin_elementwise_max(acc[ntl][mt], zero4);
          uint32_t xw0 = x0f[mt][p].u[2 * ntl + 0];
          uint32_t xw1 = x0f[mt][p].u[2 * ntl + 1];
          f32x4 xv;
          xv[0] = __uint_as_float(xw0 << 16);
          xv[1] = __uint_as_float(xw0 & 0xffff0000u);
          xv[2] = __uint_as_float(xw1 << 16);
          xv[3] = __uint_as_float(xw1 & 0xffff0000u);
          r = r + xv;
          hout[mt][p].u[2 * ntl + 0] = cvtpk(r[0], r[1]);
          hout[mt][p].u[2 * ntl + 1] = cvtpk(r[2], r[3]);
        }
    }
  };

  // ---- start layer: phases for chunks 0,1 ----
  VMW(5); barx(); stage(slotp(2), 2);        // L0c0
  start_half(slotp(0), 0);
  VMW(5); barx(); stage(slotp(0), 3);        // L0c1
  start_half(slotp(1), 1);
  #pragma unroll
  for (int mt = 0; mt < 2; ++mt)
    #pragma unroll
    for (int kt = 0; kt < 4; ++kt)
      hA[mt][kt].v = x0f[mt][kt].v;          // h = x0

  // ---- 32 layers, 2 chunks each; slots rotate mod 3; stage 2 ahead ----
  uint32_t s0 = 2;                           // slot of chunk c0 = 2+2l
  #pragma unroll 1
  for (int l = 0; l < 32; l += 2) {
    const uint32_t s1 = (s0 + 1 < 3) ? s0 + 1 : 0;
    const uint32_t s2 = (s1 + 1 < 3) ? s1 + 1 : 0;
    const uint32_t c0 = 2 + 2 * (uint32_t)l;

    // layer l half 0 (chunk c0, slot s0); stage c0+2 -> s2
    VMW(5); barx(); stage(slotp(s2), c0 + 2);
    chain_half(slotp(s0), 0, hA, hB);
    // layer l half 1 (chunk c0+1, slot s1); stage c0+3 -> s0
    VMW(5); barx(); stage(slotp(s0), c0 + 3);
    chain_half(slotp(s1), 1, hA, hB);
    // layer l+1 half 0 (chunk c0+2, slot s2); stage c0+4 -> s1
    VMW(5); barx(); if (c0 + 4 <= 66) stage(slotp(s1), c0 + 4);
    chain_half(slotp(s2), 0, hB, hA);
    // layer l+1 half 1 (chunk c0+3, slot s0); stage c0+5 -> s2
    VMW(5); barx(); if (c0 + 5 <= 66) stage(slotp(s2), c0 + 5);
    chain_half(slotp(s0), 1, hB, hA);

    s0 = s1;
  }

  // ---- output layer: chunk 66 (slot 0): W_out + b_out from LDS ----
  VMW(0); barx();
  const uint16_t* wo = slotp(0);
  const float* bob = reinterpret_cast<const float*>(wo + 8192);
  F4 bo[4];
  #pragma unroll
  for (int nt = 0; nt < 4; ++nt)
    bo[nt].f = *reinterpret_cast<const float4*>(bob + nt * 16 + q * 4);
  f32x4 ao[4][2];  // [nt][mt]
  __builtin_amdgcn_s_setprio(1);
  #pragma unroll
  for (int kt = 0; kt < 4; ++kt) {
    #pragma unroll
    for (int nt = 0; nt < 4; ++nt) {
      Frag wf;
      wf.v = *reinterpret_cast<const bs8*>(wo + ((nt * 4 + kt) * 64 + lane) * 8);
      #pragma unroll
      for (int mt = 0; mt < 2; ++mt) {
        f32x4 c = (kt == 0) ? bo[nt].v : ao[nt][mt];
        ao[nt][mt] = __builtin_amdgcn_mfma_f32_16x16x32_bf16(wf.v, hA[mt][kt].v, c, 0, 0, 0);
      }
    }
  }
  __builtin_amdgcn_s_setprio(0);

  // ---- softmax over 64 classes + transposed store via LDS scratch ----
  // Scratch lives in slots 1..2 (bytes 16640+): slot 0 (W_out) still being
  // read by other waves; slots 1/2 reads all completed before the barrier.
  float* tr = reinterpret_cast<float*>(reinterpret_cast<char*>(lds) + 16640)
              + wave * 1088;                 // 16x68 floats per wave
  #pragma unroll
  for (int mt = 0; mt < 2; ++mt) {
    float e[16];
    float M = -3.0e38f;
    #pragma unroll
    for (int nt = 0; nt < 4; ++nt)
      #pragma unroll
      for (int r = 0; r < 4; ++r)
        M = fmaxf(M, ao[nt][mt][r]);
    M = fmaxf(M, __shfl_xor(M, 16, 64));
    M = fmaxf(M, __shfl_xor(M, 32, 64));
    float S = 0.0f;
    #pragma unroll
    for (int nt = 0; nt < 4; ++nt)
      #pragma unroll
      for (int r = 0; r < 4; ++r) {
        float t = exp2f((ao[nt][mt][r] - M) * 1.4426950408889634f);
        e[nt * 4 + r] = t;
        S += t;
      }
    S += __shfl_xor(S, 16, 64);
    S += __shfl_xor(S, 32, 64);
    const float inv = 1.0f / S;
    #pragma unroll
    for (int nt = 0; nt < 4; ++nt) {
      float4 pv;
      pv.x = e[nt * 4 + 0] * inv;
      pv.y = e[nt * 4 + 1] * inv;
      pv.z = e[nt * 4 + 2] * inv;
      pv.w = e[nt * 4 + 3] * inv;
      *reinterpret_cast<float4*>(tr + mc * 68 + nt * 16 + q * 4) = pv;
    }
    __asm__ volatile("s_waitcnt lgkmcnt(0)" ::: "memory");
    #pragma unroll
    for (int it = 0; it < 4; ++it) {
      int row = it * 4 + (lane >> 4);
      float4 v = *reinterpret_cast<const float4*>(tr + row * 68 + (lane & 15) * 4);
      long gr = batch0 + mt * 16 + row;
      *reinterpret_cast<float4*>(out + gr * 64 + (lane & 15) * 4) = v;
    }
    __asm__ volatile("s_waitcnt lgkmcnt(0)" ::: "memory");
  }
}

// ---------------------------------------------------------------------------
extern "C" void kernel_launch(void* const* d_in, const int* in_sizes, int n_in,
                              void* d_out, int out_size, void* d_ws, size_t ws_size,
                              hipStream_t stream) {
  const float* x        = (const float*)d_in[0];
  const float* w_start  = (const float*)d_in[1];
  const float* b_start  = (const float*)d_in[2];
  const float* masked_w = (const float*)d_in[3];
  const float* layer_b  = (const float*)d_in[4];
  const float* w_out    = (const float*)d_in[5];
  const float* b_out    = (const float*)d_in[6];
  uint16_t* wfrag = (uint16_t*)d_ws;   // 67 chunks x 16640 B = 1,114,880 B

  prep_frags<<<273, 256, 0, stream>>>(w_start, b_start, masked_w, layer_b,
                                      w_out, b_out, wfrag);
  wann_main<<<1024, 256, 49920, stream>>>(x, wfrag, (float*)d_out);
}